// Round 18
// baseline (476.809 us; speedup 1.0000x reference)
//
#include <hip/hip_runtime.h>
#include <hip/hip_bf16.h>

#define N_NODES 100000
#define N_EDGES 1600000
#define SLOPE_ 0.2f
#define NBK 196       // row buckets of 512
#define NGRP 8        // counter groups (blockIdx&7)
#define BCAPG 1280    // per-(bucket,group) capacity (mean 1024 + 8 sigma)
#define BCAP 9216     // logical per-bucket cap used by passB
#define NCB 13        // col buckets (col>>13), 13*8192 >= 100000
#define KEYS (512 * NCB)
#define BINBLK 256    // binning blocks; chunk = E/256 = 6250
#define PREPW 20      // W-panel prep blocks
#define PMBLK 1563    // packmask blocks (8192 floats each, ballot-packed)

typedef __attribute__((ext_vector_type(8))) short bf16x8;
typedef __attribute__((ext_vector_type(4))) float f32x4;

__device__ __forceinline__ short f2bf(float f) {
    __hip_bfloat16 h = __float2bfloat16(f);
    return *reinterpret_cast<short*>(&h);
}
__device__ __forceinline__ float bflo(unsigned u) { return __uint_as_float(u << 16); }
__device__ __forceinline__ float bfhi(unsigned u) { return __uint_as_float(u & 0xFFFF0000u); }
__device__ __forceinline__ float bf2f(short s) {
    return __uint_as_float(((unsigned)(unsigned short)s) << 16);
}
__device__ __forceinline__ float lrelu_(float v) { return v > 0.f ? v : SLOPE_ * v; }

// ---------------- tiny zero kernel ----------------

__global__ void zero_k(int* __restrict__ cur8) {
    for (int i = threadIdx.x; i < NBK * NGRP; i += 256) cur8[i] = 0;
}

// ---------------- passA + prep fused (round-13 form; CSR build at an
// un-modeled ~58us floor -- 4 structural theories falsified, frozen) ----------------

__global__ void passA_k(const int* __restrict__ row, const int* __restrict__ col,
                        const float* __restrict__ ew, int* __restrict__ cur8,
                        int2* __restrict__ binned,
                        const float* __restrict__ W1, const float* __restrict__ W2,
                        const float* __restrict__ mask,
                        short* __restrict__ Bp1, short* __restrict__ Bp2,
                        unsigned* __restrict__ mp) {
    int t = threadIdx.x;
    if (blockIdx.x < BINBLK) {
        __shared__ int hist[NBK], base[NBK], off[NBK];
        int g = blockIdx.x & (NGRP - 1);
        const int chunk = N_EDGES / BINBLK;  // 6250
        int e0 = blockIdx.x * chunk;
        for (int i = t; i < NBK; i += 256) { hist[i] = 0; off[i] = 0; }
        __syncthreads();
        for (int i = t; i < chunk; i += 256)
            atomicAdd(&hist[row[e0 + i] >> 9], 1);  // LDS atomic
        __syncthreads();
        for (int i = t; i < NBK; i += 256)
            base[i] = atomicAdd(&cur8[i * NGRP + g], hist[i]);
        __syncthreads();
        for (int i = t; i < chunk; i += 256) {
            int e = e0 + i;
            int r = row[e], c = col[e];
            int b = r >> 9;
            int p = base[b] + atomicAdd(&off[b], 1);  // LDS atomic
            if (p < BCAPG)
                binned[((size_t)(b * NGRP + g)) * BCAPG + p] =
                    make_int2(((r & 511) << 17) | c, __float_as_int(ew[e]));
        }
        return;
    }
    int bi = blockIdx.x - BINBLK;
    if (bi < PREPW) {  // W panels
        int i = bi * 256 + t;
        if (i < 4096) {  // gemm1 B: K=256, NT=8
            int ln = i & 15, nt = (i >> 4) & 7, g = (i >> 7) & 3, ks = i >> 9;
            int n = nt * 16 + ln, k0 = ks * 32 + g * 8;
            bf16x8 v;
#pragma unroll
            for (int j = 0; j < 8; j++) v[j] = f2bf(W1[(k0 + j) * 128 + n]);
            *(bf16x8*)(Bp1 + (size_t)i * 8) = v;
        } else if (i < 5120) {  // gemm2 B: K=128, NT=4
            int c = i - 4096;
            int ln = c & 15, nt = (c >> 4) & 3, g = (c >> 6) & 3, ks = c >> 8;
            int n = nt * 16 + ln, k0 = ks * 32 + g * 8;
            bf16x8 v;
#pragma unroll
            for (int j = 0; j < 8; j++) v[j] = f2bf(W2[(k0 + j) * 64 + n]);
            *(bf16x8*)(Bp2 + (size_t)c * 8) = v;
        }
        return;
    }
    // packmask via ballot: block covers 8192 consecutive floats, coalesced
    int pb = bi - PREPW;
    long fbase = (long)pb * 8192;
    int wv = t >> 6, lane = t & 63;
    const long FLIM = (long)N_NODES * 128;  // 12.8M
    for (int it = 0; it < 32; ++it) {
        long f = fbase + it * 256 + wv * 64 + lane;
        float v = (f < FLIM) ? mask[f] : 0.f;
        unsigned long long bl = __ballot(v != 0.f);
        if (lane == 0) {
            long w = f >> 5;  // even word index
            if (w < (long)N_NODES * 4)
                *(unsigned long long*)(mp + w) = bl;
        }
    }
}

// passB: one block per bucket (8 staging segments). LDS counting sort by
// key = localrow*NCB + col>>13. Packed metadata: col<<15 | (bf16(w)&0x7FFF).

__global__ void __launch_bounds__(512) passB_k(const int2* __restrict__ binned,
                                               const int* __restrict__ cur8,
                                               unsigned* __restrict__ cw,
                                               int* __restrict__ row_ptr) {
    __shared__ int hist[KEYS];
    __shared__ int offs[KEYS];
    __shared__ int ssum[512];
    __shared__ int bexc[256];
    int t = threadIdx.x, b = blockIdx.x;

    int cnt_g[NGRP];
    int cnt = 0;
#pragma unroll
    for (int g = 0; g < NGRP; g++) {
        cnt_g[g] = min(cur8[b * NGRP + g], BCAPG);
        cnt += cnt_g[g];
    }
    if (cnt > BCAP) cnt = BCAP;

    if (t < 256) {
        int tot = 0;
        if (t < NBK) {
#pragma unroll
            for (int g = 0; g < NGRP; g++) tot += min(cur8[t * NGRP + g], BCAPG);
            if (tot > BCAP) tot = BCAP;
        }
        bexc[t] = tot;
    }
    __syncthreads();
    for (int off2 = 1; off2 < 256; off2 <<= 1) {
        int v = (t < 256 && t >= off2) ? bexc[t - off2] : 0;
        __syncthreads();
        if (t < 256) bexc[t] += v;
        __syncthreads();
    }
    int gbase = bexc[b] - cnt;

    for (int i = t; i < KEYS; i += 512) hist[i] = 0;
    __syncthreads();

#pragma unroll
    for (int g = 0; g < NGRP; g++) {
        const int2* src = binned + ((size_t)(b * NGRP + g)) * BCAPG;
        int cg = cnt_g[g];
        for (int i = t; i < cg; i += 512) {
            int2 v = src[i];
            int c = v.x & 0x1FFFF, lr = v.x >> 17;
            atomicAdd(&hist[lr * NCB + (c >> 13)], 1);
        }
    }
    __syncthreads();

    int loc[NCB];
    int tot = 0;
#pragma unroll
    for (int j = 0; j < NCB; j++) {
        loc[j] = tot;
        tot += hist[t * NCB + j];
    }
    ssum[t] = tot;
    __syncthreads();
    for (int off2 = 1; off2 < 512; off2 <<= 1) {
        int v = (t >= off2) ? ssum[t - off2] : 0;
        __syncthreads();
        ssum[t] += v;
        __syncthreads();
    }
    int base = ssum[t] - tot;
#pragma unroll
    for (int j = 0; j < NCB; j++) offs[t * NCB + j] = base + loc[j];

    int grow = b * 512 + t;
    if (grow <= N_NODES) row_ptr[grow] = gbase + base;
    __syncthreads();

#pragma unroll
    for (int g = 0; g < NGRP; g++) {
        const int2* src = binned + ((size_t)(b * NGRP + g)) * BCAPG;
        int cg = cnt_g[g];
        for (int i = t; i < cg; i += 512) {
            int2 v = src[i];
            int c = v.x & 0x1FFFF, lr = v.x >> 17;
            int p = gbase + atomicAdd(&offs[lr * NCB + (c >> 13)], 1);
            unsigned wb = (unsigned)(unsigned short)f2bf(__int_as_float(v.y));
            cw[p] = ((unsigned)c << 15) | (wb & 0x7FFFu);
        }
    }
}

// ---------------- skinny MFMA GEMM (B panel in LDS, A streamed to regs) ----------------
// SLICE=true writes output slice-major: out[(nt*M + row)*16 + ln] so that each
// 16-dim slice is contiguous (one XCD's spmm gather window = 3.2MB, L2-fits).

template <int K, int COLS, bool ABF16, bool SLICE>
__global__ __launch_bounds__(512) void gemm_p(const void* __restrict__ Ap,
                                              const short* __restrict__ Bp,
                                              short* __restrict__ out, int M) {
    constexpr int NT = COLS / 16;
    constexpr int NKS = K / 32;
    __shared__ short Bs[K * COLS];
    int t = threadIdx.x;
    for (int i = t; i < K * COLS / 8; i += 512)
        *(bf16x8*)(Bs + (size_t)i * 8) = *(const bf16x8*)(Bp + (size_t)i * 8);
    __syncthreads();

    int l = t & 63, wv = t >> 6;
    int ln = l & 15, g = l >> 4;
    int row0 = blockIdx.x * 256 + wv * 32;
    int r0 = row0 + ln, r1 = row0 + 16 + ln;
    int cr0 = min(r0, M - 1), cr1 = min(r1, M - 1);

    f32x4 acc[2][NT];
#pragma unroll
    for (int rf = 0; rf < 2; rf++)
#pragma unroll
        for (int nt = 0; nt < NT; nt++) acc[rf][nt] = (f32x4){0.f, 0.f, 0.f, 0.f};

#pragma unroll
    for (int ks = 0; ks < NKS; ks++) {
        int kk = ks * 32 + g * 8;
        bf16x8 a0, a1;
        if constexpr (ABF16) {
            a0 = *(const bf16x8*)((const short*)Ap + (size_t)cr0 * K + kk);
            a1 = *(const bf16x8*)((const short*)Ap + (size_t)cr1 * K + kk);
        } else {
            const float* p0 = (const float*)Ap + (size_t)cr0 * K + kk;
            const float* p1 = (const float*)Ap + (size_t)cr1 * K + kk;
            float4 u0 = *(const float4*)p0;
            float4 u1 = *(const float4*)(p0 + 4);
            float4 v0 = *(const float4*)p1;
            float4 v1 = *(const float4*)(p1 + 4);
            a0[0] = f2bf(u0.x); a0[1] = f2bf(u0.y); a0[2] = f2bf(u0.z); a0[3] = f2bf(u0.w);
            a0[4] = f2bf(u1.x); a0[5] = f2bf(u1.y); a0[6] = f2bf(u1.z); a0[7] = f2bf(u1.w);
            a1[0] = f2bf(v0.x); a1[1] = f2bf(v0.y); a1[2] = f2bf(v0.z); a1[3] = f2bf(v0.w);
            a1[4] = f2bf(v1.x); a1[5] = f2bf(v1.y); a1[6] = f2bf(v1.z); a1[7] = f2bf(v1.w);
        }
#pragma unroll
        for (int nt = 0; nt < NT; nt++) {
            bf16x8 b = *(const bf16x8*)(Bs + (size_t)((((ks * 4 + g) * NT + nt) * 16 + ln)) * 8);
            acc[0][nt] = __builtin_amdgcn_mfma_f32_16x16x32_bf16(a0, b, acc[0][nt], 0, 0, 0);
            acc[1][nt] = __builtin_amdgcn_mfma_f32_16x16x32_bf16(a1, b, acc[1][nt], 0, 0, 0);
        }
    }
#pragma unroll
    for (int rf = 0; rf < 2; rf++)
#pragma unroll
        for (int nt = 0; nt < NT; nt++)
#pragma unroll
            for (int r = 0; r < 4; r++) {
                int orow = row0 + rf * 16 + g * 4 + r;
                if (orow < M) {
                    if constexpr (SLICE)
                        out[((size_t)nt * M + orow) * 16 + ln] = f2bf(acc[rf][nt][r]);
                    else
                        out[(size_t)orow * COLS + nt * 16 + ln] = f2bf(acc[rf][nt][r]);
                }
            }
}

// ---------------- XCD-sliced spmm1 (D=128) ----------------
// Block handles slice s = bid&7 (lands on XCD s under round-robin dispatch);
// per-XCD gather footprint = 100000 rows x 32B (slice-major h0) = 3.2MB < 4MB
// L2. Metadata + output use non-temporal ops so the resident slice survives.
// Wave: lane = (edge-group 0..7) x (word 0..7); 8 rows per wave.

__global__ void spmm_sl(const int* __restrict__ row_ptr, const unsigned* __restrict__ cwp,
                        const unsigned* __restrict__ h0s,  // [8][N][8] u32 slice-major
                        const float* __restrict__ b1, const unsigned* __restrict__ maskp,
                        short* __restrict__ out, int n) {
    int bid = blockIdx.x;          // grid = 25000 (3125 rowgroups x 8 slices)
    int s = bid & 7;
    int rg = bid >> 3;             // 0..3124
    int wv = threadIdx.x >> 6;
    int lane = threadIdx.x & 63;
    int eg = lane >> 3, wd = lane & 7;
    int row0 = rg * 32 + wv * 8;   // 3125*32 = 100000 exact
    const unsigned* hs = h0s + (size_t)s * n * 8;

    for (int ri = 0; ri < 8; ri++) {
        int r = row0 + ri;
        int sp = __builtin_amdgcn_readfirstlane(row_ptr[r]);
        int ep = __builtin_amdgcn_readfirstlane(row_ptr[r + 1]);
        int cnt = ep - sp;
        const unsigned* pcw = cwp + sp;
        float ax = 0.f, ay = 0.f;
        for (int jb = 0; jb < cnt; jb += 8) {
            int idx = jb + eg;
            unsigned md = __builtin_nontemporal_load(pcw + idx);
            md = (idx < cnt) ? md : 0u;
            int c = (int)(md >> 15);
            float w = __uint_as_float((md & 0x7FFFu) << 16);
            unsigned u = hs[(size_t)c * 8 + wd];
            ax += w * bflo(u);
            ay += w * bfhi(u);
        }
        ax += __shfl_xor(ax, 8); ax += __shfl_xor(ax, 16); ax += __shfl_xor(ax, 32);
        ay += __shfl_xor(ay, 8); ay += __shfl_xor(ay, 16); ay += __shfl_xor(ay, 32);
        if (lane < 8) {
            int d0 = s * 16 + 2 * lane;
            float ox = lrelu_(ax + b1[d0]), oy = lrelu_(ay + b1[d0 + 1]);
            unsigned mw = maskp[(size_t)r * 4 + (d0 >> 5)];
            int sh = d0 & 31;
            ox = ((mw >> sh) & 1u) ? 2.f * ox : 0.f;
            oy = ((mw >> (sh + 1)) & 1u) ? 2.f * oy : 0.f;
            unsigned ov = (unsigned)(unsigned short)f2bf(ox) |
                          ((unsigned)(unsigned short)f2bf(oy) << 16);
            __builtin_nontemporal_store(ov, (unsigned*)out + (size_t)r * 64 + s * 8 + lane);
        }
    }
}

// ---------------- pull-SpMM D=64 (round-13 form) ----------------

__global__ void spmm2_k(const int* __restrict__ row_ptr, const unsigned* __restrict__ cwp,
                        const short* __restrict__ h,
                        const float* __restrict__ bias, short* __restrict__ out, int n) {
    int bid = blockIdx.x;
    int sbid = (bid & 7) * 3125 + (bid >> 3);  // grid must be 25000
    int wid = sbid * 4 + (int)(threadIdx.x >> 6);
    int lane = threadIdx.x & 63;
    if (wid >= n) return;
    int sp = __builtin_amdgcn_readfirstlane(row_ptr[wid]);
    int ep = __builtin_amdgcn_readfirstlane(row_ptr[wid + 1]);
    int cnt = ep - sp;
    const unsigned* pcw = cwp + sp;
    const unsigned* hb = (const unsigned*)h;
    int li = lane & 31;
    float ax = 0.f, ay = 0.f;
    for (int jb = 0; jb < cnt; jb += 8) {
        unsigned u[4];
        float w[4];
#pragma unroll
        for (int p = 0; p < 4; p++) {
            int iA = jb + 2 * p, iB = iA + 1;
            unsigned mA = pcw[iA];
            mA = (iA < cnt) ? mA : 0u;
            unsigned mB = pcw[iB];
            mB = (iB < cnt) ? mB : 0u;
            unsigned md = (lane < 32) ? mA : mB;
            int c = (int)(md >> 15);
            w[p] = __uint_as_float((md & 0x7FFFu) << 16);
            u[p] = hb[(size_t)c * 32 + li];
        }
#pragma unroll
        for (int p = 0; p < 4; p++) {
            ax += w[p] * bflo(u[p]);
            ay += w[p] * bfhi(u[p]);
        }
    }
    ax += __shfl_xor(ax, 32);
    ay += __shfl_xor(ay, 32);
    float2 b = *(const float2*)(bias + li * 2);
    float ox = lrelu_(ax + b.x), oy = lrelu_(ay + b.y);
    unsigned ov = (unsigned)(unsigned short)f2bf(ox) |
                  ((unsigned)(unsigned short)f2bf(oy) << 16);
    if (lane < 32) *(unsigned*)(out + (size_t)wid * 64 + li * 2) = ov;
}

// ---------------- fused classifier (round-13 form) ----------------

__global__ void clf_k(const short* __restrict__ h, const float* __restrict__ W3,
                      const float* __restrict__ b3, const float* __restrict__ W4,
                      const float* __restrict__ b4, float* __restrict__ out) {
    __shared__ float W3s[64][32];
    __shared__ float W4s[32][16];
    __shared__ float b3s[32], b4s[16];
    __shared__ float hs[32][64];
    __shared__ float t4[32][33];  // pad
    int t = threadIdx.x;
    for (int l = t; l < 64 * 32; l += 256) W3s[l / 32][l % 32] = W3[l];
    for (int l = t; l < 32 * 16; l += 256) W4s[l / 16][l % 16] = W4[l];
    if (t < 32) b3s[t] = b3[t];
    if (t < 16) b4s[t] = b4[t];
    int row0 = blockIdx.x * 32;
    {
        bf16x8 v = *(const bf16x8*)(h + (size_t)row0 * 64 + t * 8);
        int r = t >> 3, c0 = (t & 7) << 3;
#pragma unroll
        for (int j = 0; j < 8; j++) hs[r][c0 + j] = bf2f(v[j]);
    }
    __syncthreads();
    for (int l = t; l < 1024; l += 256) {
        int r = l / 32, c = l % 32;
        float a = b3s[c];
#pragma unroll 8
        for (int k = 0; k < 64; k++) a += hs[r][k] * W3s[k][c];
        t4[r][c] = a > 0.f ? a : SLOPE_ * a;
    }
    __syncthreads();
    for (int l = t; l < 512; l += 256) {
        int r = l / 16, c = l % 16;
        float a = b4s[c];
#pragma unroll
        for (int k = 0; k < 32; k++) a += t4[r][k] * W4s[k][c];
        out[(size_t)(row0 + r) * 16 + c] = a;
    }
}

// ---------------- launch ----------------

extern "C" void kernel_launch(void* const* d_in, const int* in_sizes, int n_in,
                              void* d_out, int out_size, void* d_ws, size_t ws_size,
                              hipStream_t stream) {
    const float* x = (const float*)d_in[0];
    const int* row = (const int*)d_in[1];
    const int* col = (const int*)d_in[2];
    const float* ew = (const float*)d_in[3];
    const float* W1 = (const float*)d_in[4];
    const float* b1 = (const float*)d_in[5];
    const float* W2 = (const float*)d_in[6];
    const float* b2 = (const float*)d_in[7];
    const float* W3 = (const float*)d_in[8];
    const float* b3 = (const float*)d_in[9];
    const float* W4 = (const float*)d_in[10];
    const float* b4 = (const float*)d_in[11];
    const float* mask = (const float*)d_in[12];
    float* out = (float*)d_out;

    const int N = N_NODES, E = N_EDGES;

    short* h0 = (short*)d_ws;              // N*128 bf16 (gemm1 out, SLICE-major)
    short* h1 = h0 + (size_t)N * 128;      // N*128 bf16 (spmm1 out, row-major)
    short* h2 = h1 + (size_t)N * 128;      // N*64  bf16 (gemm2 out)
    short* h3 = h2 + (size_t)N * 64;       // N*64  bf16 (spmm2 out)
    short* Bp1 = h3 + (size_t)N * 64;      // 32768 bf16 (fragment-ordered W1)
    short* Bp2 = Bp1 + 32768;              // 8192  bf16 (fragment-ordered W2)
    int* row_ptr = (int*)(Bp2 + 8192);     // N+1
    int* cur8 = row_ptr + N + 1;           // NBK*NGRP (+pad)
    unsigned* mask_p = (unsigned*)(cur8 + NBK * NGRP + 8);  // N*4 u32
    unsigned* cwp = mask_p + (size_t)N * 4;                 // E+16 u32
    int2* binned = (int2*)h0;              // 16.1MB, aliases h0 (consumed by
                                           // passB before gemm1 writes h0)

    zero_k<<<1, 256, 0, stream>>>(cur8);
    passA_k<<<BINBLK + PREPW + PMBLK, 256, 0, stream>>>(row, col, ew, cur8, binned,
                                                        W1, W2, mask, Bp1, Bp2, mask_p);
    passB_k<<<NBK, 512, 0, stream>>>(binned, cur8, cwp, row_ptr);

    gemm_p<256, 128, false, true><<<(N + 255) / 256, 512, 0, stream>>>(x, Bp1, h0, N);
    spmm_sl<<<25000, 256, 0, stream>>>(row_ptr, cwp, (const unsigned*)h0, b1, mask_p, h1, N);
    gemm_p<128, 64, true, false><<<(N + 255) / 256, 512, 0, stream>>>(h1, Bp2, h2, N);
    spmm2_k<<<25000, 256, 0, stream>>>(row_ptr, cwp, h2, b2, h3, N);
    clf_k<<<N / 32, 256, 0, stream>>>(h3, W3, b3, W4, b4, out);
}

// Round 19
// 222.776 us; speedup vs baseline: 2.1403x; 2.1403x over previous
//
#include <hip/hip_runtime.h>
#include <hip/hip_bf16.h>

#define N_NODES 100000
#define N_EDGES 1600000
#define SLOPE_ 0.2f
#define NBK 196       // row buckets of 512
#define NGRP 8        // counter groups (blockIdx&7)
#define BCAPG 1280    // per-(bucket,group) capacity (mean 1024 + 8 sigma)
#define BCAP 9216     // logical per-bucket cap used by passB
#define NCB 13        // col buckets (col>>13), 13*8192 >= 100000
#define KEYS (512 * NCB)
#define BINBLK 256    // binning blocks; chunk = E/256 = 6250
#define PREPW 20      // W-panel prep blocks
#define PMBLK 1563    // packmask blocks (8192 floats each, ballot-packed)

typedef __attribute__((ext_vector_type(8))) short bf16x8;
typedef __attribute__((ext_vector_type(4))) float f32x4;

__device__ __forceinline__ short f2bf(float f) {
    __hip_bfloat16 h = __float2bfloat16(f);
    return *reinterpret_cast<short*>(&h);
}
__device__ __forceinline__ float bflo(unsigned u) { return __uint_as_float(u << 16); }
__device__ __forceinline__ float bfhi(unsigned u) { return __uint_as_float(u & 0xFFFF0000u); }
__device__ __forceinline__ float bf2f(short s) {
    return __uint_as_float(((unsigned)(unsigned short)s) << 16);
}

// ---------------- tiny zero kernel (in-graph hipMemsetAsync costs ~60us as a
// fill kernel -- measured round 9/10) ----------------

__global__ void zero_k(int* __restrict__ cur8) {
    for (int i = threadIdx.x; i < NBK * NGRP; i += 256) cur8[i] = 0;
}

// ---------------- passA + prep fused (round-13 form; CSR build at an
// un-modeled ~58us floor -- 4 structural theories falsified in rounds 13-18,
// frozen as the best-measured configuration) ----------------

__global__ void passA_k(const int* __restrict__ row, const int* __restrict__ col,
                        const float* __restrict__ ew, int* __restrict__ cur8,
                        int2* __restrict__ binned,
                        const float* __restrict__ W1, const float* __restrict__ W2,
                        const float* __restrict__ mask,
                        short* __restrict__ Bp1, short* __restrict__ Bp2,
                        unsigned* __restrict__ mp) {
    int t = threadIdx.x;
    if (blockIdx.x < BINBLK) {
        __shared__ int hist[NBK], base[NBK], off[NBK];
        int g = blockIdx.x & (NGRP - 1);
        const int chunk = N_EDGES / BINBLK;  // 6250
        int e0 = blockIdx.x * chunk;
        for (int i = t; i < NBK; i += 256) { hist[i] = 0; off[i] = 0; }
        __syncthreads();
        for (int i = t; i < chunk; i += 256)
            atomicAdd(&hist[row[e0 + i] >> 9], 1);  // LDS atomic
        __syncthreads();
        for (int i = t; i < NBK; i += 256)
            base[i] = atomicAdd(&cur8[i * NGRP + g], hist[i]);
        __syncthreads();
        for (int i = t; i < chunk; i += 256) {
            int e = e0 + i;
            int r = row[e], c = col[e];
            int b = r >> 9;
            int p = base[b] + atomicAdd(&off[b], 1);  // LDS atomic
            if (p < BCAPG)
                binned[((size_t)(b * NGRP + g)) * BCAPG + p] =
                    make_int2(((r & 511) << 17) | c, __float_as_int(ew[e]));
        }
        return;
    }
    int bi = blockIdx.x - BINBLK;
    if (bi < PREPW) {  // W panels
        int i = bi * 256 + t;
        if (i < 4096) {  // gemm1 B: K=256, NT=8
            int ln = i & 15, nt = (i >> 4) & 7, g = (i >> 7) & 3, ks = i >> 9;
            int n = nt * 16 + ln, k0 = ks * 32 + g * 8;
            bf16x8 v;
#pragma unroll
            for (int j = 0; j < 8; j++) v[j] = f2bf(W1[(k0 + j) * 128 + n]);
            *(bf16x8*)(Bp1 + (size_t)i * 8) = v;
        } else if (i < 5120) {  // gemm2 B: K=128, NT=4
            int c = i - 4096;
            int ln = c & 15, nt = (c >> 4) & 3, g = (c >> 6) & 3, ks = c >> 8;
            int n = nt * 16 + ln, k0 = ks * 32 + g * 8;
            bf16x8 v;
#pragma unroll
            for (int j = 0; j < 8; j++) v[j] = f2bf(W2[(k0 + j) * 64 + n]);
            *(bf16x8*)(Bp2 + (size_t)c * 8) = v;
        }
        return;
    }
    // packmask via ballot: block covers 8192 consecutive floats, coalesced
    int pb = bi - PREPW;
    long fbase = (long)pb * 8192;
    int wv = t >> 6, lane = t & 63;
    const long FLIM = (long)N_NODES * 128;  // 12.8M
    for (int it = 0; it < 32; ++it) {
        long f = fbase + it * 256 + wv * 64 + lane;
        float v = (f < FLIM) ? mask[f] : 0.f;
        unsigned long long bl = __ballot(v != 0.f);
        if (lane == 0) {
            long w = f >> 5;  // even word index
            if (w < (long)N_NODES * 4)
                *(unsigned long long*)(mp + w) = bl;
        }
    }
}

// passB: one block per bucket (8 staging segments). LDS counting sort by
// key = localrow*NCB + col>>13. Emits packed metadata:
// col<<15 | (bf16(w) & 0x7FFF)  (w >= 0 -> sign bit free), and row_ptr.

__global__ void __launch_bounds__(512) passB_k(const int2* __restrict__ binned,
                                               const int* __restrict__ cur8,
                                               unsigned* __restrict__ cw,
                                               int* __restrict__ row_ptr) {
    __shared__ int hist[KEYS];
    __shared__ int offs[KEYS];
    __shared__ int ssum[512];
    __shared__ int bexc[256];
    int t = threadIdx.x, b = blockIdx.x;

    int cnt_g[NGRP];
    int cnt = 0;
#pragma unroll
    for (int g = 0; g < NGRP; g++) {
        cnt_g[g] = min(cur8[b * NGRP + g], BCAPG);
        cnt += cnt_g[g];
    }
    if (cnt > BCAP) cnt = BCAP;

    if (t < 256) {
        int tot = 0;
        if (t < NBK) {
#pragma unroll
            for (int g = 0; g < NGRP; g++) tot += min(cur8[t * NGRP + g], BCAPG);
            if (tot > BCAP) tot = BCAP;
        }
        bexc[t] = tot;
    }
    __syncthreads();
    for (int off2 = 1; off2 < 256; off2 <<= 1) {
        int v = (t < 256 && t >= off2) ? bexc[t - off2] : 0;
        __syncthreads();
        if (t < 256) bexc[t] += v;
        __syncthreads();
    }
    int gbase = bexc[b] - cnt;

    for (int i = t; i < KEYS; i += 512) hist[i] = 0;
    __syncthreads();

#pragma unroll
    for (int g = 0; g < NGRP; g++) {
        const int2* src = binned + ((size_t)(b * NGRP + g)) * BCAPG;
        int cg = cnt_g[g];
        for (int i = t; i < cg; i += 512) {
            int2 v = src[i];
            int c = v.x & 0x1FFFF, lr = v.x >> 17;
            atomicAdd(&hist[lr * NCB + (c >> 13)], 1);
        }
    }
    __syncthreads();

    int loc[NCB];
    int tot = 0;
#pragma unroll
    for (int j = 0; j < NCB; j++) {
        loc[j] = tot;
        tot += hist[t * NCB + j];
    }
    ssum[t] = tot;
    __syncthreads();
    for (int off2 = 1; off2 < 512; off2 <<= 1) {
        int v = (t >= off2) ? ssum[t - off2] : 0;
        __syncthreads();
        ssum[t] += v;
        __syncthreads();
    }
    int base = ssum[t] - tot;
#pragma unroll
    for (int j = 0; j < NCB; j++) offs[t * NCB + j] = base + loc[j];

    int grow = b * 512 + t;
    if (grow <= N_NODES) row_ptr[grow] = gbase + base;
    __syncthreads();

#pragma unroll
    for (int g = 0; g < NGRP; g++) {
        const int2* src = binned + ((size_t)(b * NGRP + g)) * BCAPG;
        int cg = cnt_g[g];
        for (int i = t; i < cg; i += 512) {
            int2 v = src[i];
            int c = v.x & 0x1FFFF, lr = v.x >> 17;
            int p = gbase + atomicAdd(&offs[lr * NCB + (c >> 13)], 1);
            unsigned wb = (unsigned)(unsigned short)f2bf(__int_as_float(v.y));
            cw[p] = ((unsigned)c << 15) | (wb & 0x7FFFu);
        }
    }
}

// ---------------- skinny MFMA GEMM (B panel in LDS, A streamed to regs) ----------------

template <int K, int COLS, bool ABF16>
__global__ __launch_bounds__(512) void gemm_p(const void* __restrict__ Ap,
                                              const short* __restrict__ Bp,
                                              short* __restrict__ out, int M) {
    constexpr int NT = COLS / 16;
    constexpr int NKS = K / 32;
    __shared__ short Bs[K * COLS];
    int t = threadIdx.x;
    for (int i = t; i < K * COLS / 8; i += 512)
        *(bf16x8*)(Bs + (size_t)i * 8) = *(const bf16x8*)(Bp + (size_t)i * 8);
    __syncthreads();

    int l = t & 63, wv = t >> 6;
    int ln = l & 15, g = l >> 4;
    int row0 = blockIdx.x * 256 + wv * 32;
    int r0 = row0 + ln, r1 = row0 + 16 + ln;
    int cr0 = min(r0, M - 1), cr1 = min(r1, M - 1);

    f32x4 acc[2][NT];
#pragma unroll
    for (int rf = 0; rf < 2; rf++)
#pragma unroll
        for (int nt = 0; nt < NT; nt++) acc[rf][nt] = (f32x4){0.f, 0.f, 0.f, 0.f};

#pragma unroll
    for (int ks = 0; ks < NKS; ks++) {
        int kk = ks * 32 + g * 8;
        bf16x8 a0, a1;
        if constexpr (ABF16) {
            a0 = *(const bf16x8*)((const short*)Ap + (size_t)cr0 * K + kk);
            a1 = *(const bf16x8*)((const short*)Ap + (size_t)cr1 * K + kk);
        } else {
            const float* p0 = (const float*)Ap + (size_t)cr0 * K + kk;
            const float* p1 = (const float*)Ap + (size_t)cr1 * K + kk;
            float4 u0 = *(const float4*)p0;
            float4 u1 = *(const float4*)(p0 + 4);
            float4 v0 = *(const float4*)p1;
            float4 v1 = *(const float4*)(p1 + 4);
            a0[0] = f2bf(u0.x); a0[1] = f2bf(u0.y); a0[2] = f2bf(u0.z); a0[3] = f2bf(u0.w);
            a0[4] = f2bf(u1.x); a0[5] = f2bf(u1.y); a0[6] = f2bf(u1.z); a0[7] = f2bf(u1.w);
            a1[0] = f2bf(v0.x); a1[1] = f2bf(v0.y); a1[2] = f2bf(v0.z); a1[3] = f2bf(v0.w);
            a1[4] = f2bf(v1.x); a1[5] = f2bf(v1.y); a1[6] = f2bf(v1.z); a1[7] = f2bf(v1.w);
        }
#pragma unroll
        for (int nt = 0; nt < NT; nt++) {
            bf16x8 b = *(const bf16x8*)(Bs + (size_t)((((ks * 4 + g) * NT + nt) * 16 + ln)) * 8);
            acc[0][nt] = __builtin_amdgcn_mfma_f32_16x16x32_bf16(a0, b, acc[0][nt], 0, 0, 0);
            acc[1][nt] = __builtin_amdgcn_mfma_f32_16x16x32_bf16(a1, b, acc[1][nt], 0, 0, 0);
        }
    }
#pragma unroll
    for (int rf = 0; rf < 2; rf++)
#pragma unroll
        for (int nt = 0; nt < NT; nt++)
#pragma unroll
            for (int r = 0; r < 4; r++) {
                int orow = row0 + rf * 16 + g * 4 + r;
                if (orow < M) out[(size_t)orow * COLS + nt * 16 + ln] = f2bf(acc[rf][nt][r]);
            }
}

// ---------------- pull-SpMM, scalar metadata path ----------------

template <int D, bool DROP>
__global__ void spmm_bf(const int* __restrict__ row_ptr, const unsigned* __restrict__ cwp,
                        const short* __restrict__ h,
                        const float* __restrict__ bias, const unsigned* __restrict__ maskp,
                        short* __restrict__ out, int n) {
    int bid = blockIdx.x;
    int sbid = (bid & 7) * 3125 + (bid >> 3);  // grid must be 25000
    int wid = sbid * 4 + (int)(threadIdx.x >> 6);
    int lane = threadIdx.x & 63;
    if (wid >= n) return;
    int sp = __builtin_amdgcn_readfirstlane(row_ptr[wid]);
    int ep = __builtin_amdgcn_readfirstlane(row_ptr[wid + 1]);
    int cnt = ep - sp;
    const unsigned* pcw = cwp + sp;
    const unsigned* hb = (const unsigned*)h;
    float ax = 0.f, ay = 0.f;

    if (D == 128) {
        for (int jb = 0; jb < cnt; jb += 8) {
            unsigned u[8];
            float w[8];
#pragma unroll
            for (int p = 0; p < 8; p++) {
                int idx = jb + p;
                unsigned md = pcw[idx];
                md = (idx < cnt) ? md : 0u;
                int c = (int)(md >> 15);
                w[p] = __uint_as_float((md & 0x7FFFu) << 16);
                u[p] = hb[(size_t)c * 64 + lane];
            }
#pragma unroll
            for (int p = 0; p < 8; p++) {
                ax += w[p] * bflo(u[p]);
                ay += w[p] * bfhi(u[p]);
            }
        }
        float2 b = *(const float2*)(bias + 2 * lane);
        float ox = ax + b.x, oy = ay + b.y;
        ox = ox > 0.f ? ox : SLOPE_ * ox;
        oy = oy > 0.f ? oy : SLOPE_ * oy;
        if (DROP) {
            unsigned mw = maskp[(size_t)wid * 4 + (lane >> 4)];
            unsigned sh = (2 * lane) & 31;
            ox = ((mw >> sh) & 1u) ? 2.f * ox : 0.f;
            oy = ((mw >> (sh + 1)) & 1u) ? 2.f * oy : 0.f;
        }
        unsigned ov = (unsigned)(unsigned short)f2bf(ox) |
                      ((unsigned)(unsigned short)f2bf(oy) << 16);
        *(unsigned*)(out + (size_t)wid * 128 + 2 * lane) = ov;
    } else {  // D == 64: lanes 0-31 = even edge, 32-63 = odd edge
        int li = lane & 31;
        for (int jb = 0; jb < cnt; jb += 8) {
            unsigned u[4];
            float w[4];
#pragma unroll
            for (int p = 0; p < 4; p++) {
                int iA = jb + 2 * p, iB = iA + 1;
                unsigned mA = pcw[iA];
                mA = (iA < cnt) ? mA : 0u;
                unsigned mB = pcw[iB];
                mB = (iB < cnt) ? mB : 0u;
                unsigned md = (lane < 32) ? mA : mB;
                int c = (int)(md >> 15);
                w[p] = __uint_as_float((md & 0x7FFFu) << 16);
                u[p] = hb[(size_t)c * 32 + li];
            }
#pragma unroll
            for (int p = 0; p < 4; p++) {
                ax += w[p] * bflo(u[p]);
                ay += w[p] * bfhi(u[p]);
            }
        }
        ax += __shfl_xor(ax, 32);
        ay += __shfl_xor(ay, 32);
        float2 b = *(const float2*)(bias + li * 2);
        float ox = ax + b.x, oy = ay + b.y;
        ox = ox > 0.f ? ox : SLOPE_ * ox;
        oy = oy > 0.f ? oy : SLOPE_ * oy;
        unsigned ov = (unsigned)(unsigned short)f2bf(ox) |
                      ((unsigned)(unsigned short)f2bf(oy) << 16);
        if (lane < 32) *(unsigned*)(out + (size_t)wid * 64 + li * 2) = ov;
    }
}

// ---------------- fused classifier: out = lrelu(h@W3+b3)@W4 + b4 (h bf16) ----------------

__global__ void clf_k(const short* __restrict__ h, const float* __restrict__ W3,
                      const float* __restrict__ b3, const float* __restrict__ W4,
                      const float* __restrict__ b4, float* __restrict__ out) {
    __shared__ float W3s[64][32];
    __shared__ float W4s[32][16];
    __shared__ float b3s[32], b4s[16];
    __shared__ float hs[32][64];
    __shared__ float t4[32][33];  // pad
    int t = threadIdx.x;
    for (int l = t; l < 64 * 32; l += 256) W3s[l / 32][l % 32] = W3[l];
    for (int l = t; l < 32 * 16; l += 256) W4s[l / 16][l % 16] = W4[l];
    if (t < 32) b3s[t] = b3[t];
    if (t < 16) b4s[t] = b4[t];
    int row0 = blockIdx.x * 32;
    {
        bf16x8 v = *(const bf16x8*)(h + (size_t)row0 * 64 + t * 8);
        int r = t >> 3, c0 = (t & 7) << 3;
#pragma unroll
        for (int j = 0; j < 8; j++) hs[r][c0 + j] = bf2f(v[j]);
    }
    __syncthreads();
    for (int l = t; l < 1024; l += 256) {
        int r = l / 32, c = l % 32;
        float a = b3s[c];
#pragma unroll 8
        for (int k = 0; k < 64; k++) a += hs[r][k] * W3s[k][c];
        t4[r][c] = a > 0.f ? a : SLOPE_ * a;
    }
    __syncthreads();
    for (int l = t; l < 512; l += 256) {
        int r = l / 16, c = l % 16;
        float a = b4s[c];
#pragma unroll
        for (int k = 0; k < 32; k++) a += t4[r][k] * W4s[k][c];
        out[(size_t)(row0 + r) * 16 + c] = a;
    }
}

// ---------------- launch ----------------

extern "C" void kernel_launch(void* const* d_in, const int* in_sizes, int n_in,
                              void* d_out, int out_size, void* d_ws, size_t ws_size,
                              hipStream_t stream) {
    const float* x = (const float*)d_in[0];
    const int* row = (const int*)d_in[1];
    const int* col = (const int*)d_in[2];
    const float* ew = (const float*)d_in[3];
    const float* W1 = (const float*)d_in[4];
    const float* b1 = (const float*)d_in[5];
    const float* W2 = (const float*)d_in[6];
    const float* b2 = (const float*)d_in[7];
    const float* W3 = (const float*)d_in[8];
    const float* b3 = (const float*)d_in[9];
    const float* W4 = (const float*)d_in[10];
    const float* b4 = (const float*)d_in[11];
    const float* mask = (const float*)d_in[12];
    float* out = (float*)d_out;

    const int N = N_NODES, E = N_EDGES;

    short* h0 = (short*)d_ws;              // N*128 bf16 (gemm1 out)
    short* h1 = h0 + (size_t)N * 128;      // N*128 bf16 (spmm1 out)
    short* h2 = h1 + (size_t)N * 128;      // N*64  bf16 (gemm2 out)
    short* h3 = h2 + (size_t)N * 64;       // N*64  bf16 (spmm2 out)
    short* Bp1 = h3 + (size_t)N * 64;      // 32768 bf16 (fragment-ordered W1)
    short* Bp2 = Bp1 + 32768;              // 8192  bf16 (fragment-ordered W2)
    int* row_ptr = (int*)(Bp2 + 8192);     // N+1
    int* cur8 = row_ptr + N + 1;           // NBK*NGRP (+pad)
    unsigned* mask_p = (unsigned*)(cur8 + NBK * NGRP + 8);  // N*4 u32
    unsigned* cwp = mask_p + (size_t)N * 4;                 // E+16 u32
    int2* binned = (int2*)h0;              // NBK*NGRP*BCAPG int2 = 16.1MB,
                                           // aliases h0 (consumed by passB
                                           // before gemm1 writes h0)

    zero_k<<<1, 256, 0, stream>>>(cur8);
    passA_k<<<BINBLK + PREPW + PMBLK, 256, 0, stream>>>(row, col, ew, cur8, binned,
                                                        W1, W2, mask, Bp1, Bp2, mask_p);
    passB_k<<<NBK, 512, 0, stream>>>(binned, cur8, cwp, row_ptr);

    gemm_p<256, 128, false><<<(N + 255) / 256, 512, 0, stream>>>(x, Bp1, h0, N);
    spmm_bf<128, true><<<25000, 256, 0, stream>>>(row_ptr, cwp, h0, b1, mask_p, h1, N);
    gemm_p<128, 64, true><<<(N + 255) / 256, 512, 0, stream>>>(h1, Bp2, h2, N);
    spmm_bf<64, false><<<25000, 256, 0, stream>>>(row_ptr, cwp, h2, b2, nullptr, h3, N);
    clf_k<<<N / 32, 256, 0, stream>>>(h3, W3, b3, W4, b4, out);
}